// Round 7
// baseline (202.716 us; speedup 1.0000x reference)
//
#include <hip/hip_runtime.h>
#include <math.h>

// ---------------------------------------------------------------------------
// AttentionAggregator round 7:
//  R6 was LDS-read-bound (384 KB/CU-iter vs 85 B/cyc). Fixes:
//  1) S^T trick: compute S^T = K*Q^T so the 32x32 C-layout puts q on the lane
//     axis; C regs [8a..8a+7] form a PV A-frag verbatim under the key
//     permutation key = 32kt + 16a + 4h + 8(i>>2) + (i&3), which is baked
//     into the V gather. P never touches LDS (no round-trip, no lgkm chain).
//  2) wave = 64 rows x 256 cols -> each bv LDS read feeds 2 MFMAs.
//     LDS/CU-iter: 160 KB (~1900 cyc) < MFMA 2304 cyc -> MFMA-bound.
//  - o[2][8] = 256 acc VGPRs -> launch_bounds(256,1), ~1 wave/SIMD, ~404 live
//    regs (hbm_bytes is the spill sentinel; R4 taught us what spill looks like)
//  - l denom: per-lane scalar += , final shfl_xor(32) only.
//  - prep+gather fused; final float4.
// ---------------------------------------------------------------------------
#define NR 8192
#define DQ 32
#define DV 256
#define OUT_DIM 64
#define NSPLIT 4
#define BK 64
#define NIT ((NR / NSPLIT) / BK)      // 32
// 2^-1.25 * sqrt(log2(e)): qh = q*QS2 -> dot = (q.q')/sqrt(32)*log2(e); p=2^s
#define QSCALE2 0.5050114839784955f

typedef short short4v __attribute__((ext_vector_type(4)));
typedef short short8 __attribute__((ext_vector_type(8)));   // 8 bf16
typedef float f32x16 __attribute__((ext_vector_type(16)));  // 32x32 MFMA acc
typedef unsigned int u32;
typedef __attribute__((address_space(1))) const u32 gas_t;
typedef __attribute__((address_space(3))) u32 las_t;

__device__ __forceinline__ unsigned short f32_to_bf16(float f) {
    union { float f; unsigned int u; } v; v.f = f;
    unsigned int u = v.u + 0x7FFFu + ((v.u >> 16) & 1u);    // RNE
    return (unsigned short)(u >> 16);
}
__device__ __forceinline__ float exp2_fast(float x) {
#if __has_builtin(__builtin_amdgcn_exp2f)
    return __builtin_amdgcn_exp2f(x);
#else
    return exp2f(x);
#endif
}

// ---------------------------------------------------------------------------
// prep+gather fused.
// b in [0,1040): zero acc+lsum | [1040,1552): qconv | [1552,1568): wconv |
// [1568,1824): gather (one 64-key V tile per block, permuted frag layout).
// ---------------------------------------------------------------------------
__global__ void prep_gather_kernel(
        const float* __restrict__ review,
        const float* __restrict__ user,
        const float* __restrict__ item,
        const int* __restrict__ adj_ur, const int* __restrict__ adj_ri,
        const int* __restrict__ adj_ir, const int* __restrict__ adj_ru,
        const float* __restrict__ Wu,  const float* __restrict__ Wi,
        float4* __restrict__ accz,
        unsigned short* __restrict__ qh,
        unsigned short* __restrict__ wbf,
        unsigned short* __restrict__ vt) {
    __shared__ __align__(16) unsigned short T[64][264];
    int b = blockIdx.x, t = threadIdx.x;
    if (b < 1040) {                       // zero acc+lsum (4.26 MB)
        accz[b * 256 + t] = make_float4(0.f, 0.f, 0.f, 0.f);
        return;
    }
    b -= 1040;
    if (b < 512) {                        // qconv
        int i = (b * 256 + t) * 4;
        int side  = i >= NR * DQ;
        int local = i - side * NR * DQ;
        const float* src = side ? item : user;
        float4 v = *(const float4*)(src + local);
        short4v o;
        o[0] = (short)f32_to_bf16(v.x * QSCALE2);
        o[1] = (short)f32_to_bf16(v.y * QSCALE2);
        o[2] = (short)f32_to_bf16(v.z * QSCALE2);
        o[3] = (short)f32_to_bf16(v.w * QSCALE2);
        *(short4v*)(qh + i) = o;
        return;
    }
    b -= 512;
    if (b < 16) {                         // wconv: wbf[wm][p][kt][nt][lane][i]
        int g  = b * 256 + t;
        int ln = g & 31, h = (g >> 5) & 1, nt = (g >> 6) & 1;
        int kt = (g >> 7) & 3, p = (g >> 9) & 3, wm = g >> 11;
        const float* W = wm ? Wi : Wu;
        unsigned short* dst = wbf + (size_t)g * 8;
#pragma unroll
        for (int i = 0; i < 8; ++i) {
            int k = p * 64 + kt * 16 + h * 8 + i;
            dst[i] = f32_to_bf16(W[k * OUT_DIM + nt * 32 + ln]);
        }
        return;
    }
    // ---- gather: one side x 64 keys -> one 32 KB vt tile ----
    int gb   = b - 16;                    // 0..255
    int side = gb >> 7;
    int bxg  = gb & 127;
    int key0 = bxg * 64;
    const int* adjA   = side ? adj_ir : adj_ur;
    const int* adjB   = side ? adj_ru : adj_ri;
    const float* srcB = side ? user : item;
    // phase 1: coalesced row reads -> bf16 LDS tile T[key][c]
    {
        int key = t >> 2, q = t & 3;
#pragma unroll
        for (int rr = 0; rr < 2; ++rr) {
            int ss  = q * 2 + rr;
            int knb = ss >> 1, isB = ss & 1;
            int row = (isB ? adjB : adjA)[(key0 + key) * 4 + knb];
            const float4* src = (const float4*)((isB ? srcB : review) + (size_t)row * DQ);
            int dbase = knb * 64 + isB * 32;
#pragma unroll
            for (int d = 0; d < 4; ++d) {
                float4 a = src[d * 2], b2 = src[d * 2 + 1];
                short8 v;
                v[0] = (short)f32_to_bf16(a.x);  v[1] = (short)f32_to_bf16(a.y);
                v[2] = (short)f32_to_bf16(a.z);  v[3] = (short)f32_to_bf16(a.w);
                v[4] = (short)f32_to_bf16(b2.x); v[5] = (short)f32_to_bf16(b2.y);
                v[6] = (short)f32_to_bf16(b2.z); v[7] = (short)f32_to_bf16(b2.w);
                *(short8*)&T[key][dbase + d * 8] = v;
            }
        }
    }
    __syncthreads();
    // phase 2: permuted frag-native writes.
    // B-frag (g,ct,lane=(ln,h),i) = V[32kt+16a+4h+8(i>>2)+(i&3)][ct*32+ln],
    // kt=g>>1, a=g&1. dst flat offset = u*8+i with u=(g*8+ct)*64+lane.
#pragma unroll
    for (int w8 = 0; w8 < 8; ++w8) {
        int u    = t + 256 * w8;          // 0..2047
        int g    = u >> 9;
        int ct   = (u >> 6) & 7;
        int lane = u & 63;
        int ln = lane & 31, h = lane >> 5;
        int kt = g >> 1, a = g & 1;
        int col = ct * 32 + ln;
        short8 v;
#pragma unroll
        for (int i = 0; i < 8; ++i) {
            int lkey = kt * 32 + a * 16 + h * 4 + 8 * (i >> 2) + (i & 3);
            v[i] = (short)T[lkey][col];
        }
        size_t dst = (size_t)side * NR * DV + (size_t)bxg * 16384 + (size_t)u * 8;
        *(short8*)(vt + dst) = v;
    }
}

// ---------------------------------------------------------------------------
// Flash attention, S^T register-resident P, 64-row waves, LDS-shared V.
// 256 blocks x 256 thr (4 waves); bx&7 = (side,sp) XCD-affine; 1 block/CU.
// ---------------------------------------------------------------------------
__global__ __launch_bounds__(256, 1) void flash_kernel(
        const unsigned short* __restrict__ qh,
        const unsigned short* __restrict__ vt,
        const unsigned short* __restrict__ wbf,
        float* __restrict__ acc,     // [2][NR][64]
        float* __restrict__ lsum)    // [2][NR]
{
    const int bx   = blockIdx.x;
    const int side = bx & 1;
    const int sp   = (bx >> 1) & (NSPLIT - 1);
    const int rb   = bx >> 3;                  // 0..31
    const int w    = threadIdx.x >> 6;         // 0..3
    const int lane = threadIdx.x & 63;
    const int ln   = lane & 31;
    const int h    = lane >> 5;

    const int m0 = rb * 256 + w * 64;          // wave's first q-row
    const unsigned short* Q  = qh + (size_t)side * NR * DQ;
    const unsigned short* VT = vt + (size_t)side * NR * DV;
    const int t64_0 = sp * NIT;                // first 64-key tile index

    __shared__ __align__(16) unsigned short Vbuf[2][16384];  // 64 KB
    __shared__ __align__(16) unsigned short Ebuf[4][64 * 72]; // 36.9 KB epilogue

    // stage 64-key tile `tile` (global index) into Vbuf[b]: wave quarter via DMA
    auto stage = [&](int tile, int b) {
        const unsigned short* src = VT + (size_t)tile * 16384 + w * 4096 + lane * 8;
        unsigned short* dst = &Vbuf[b][w * 4096];
#pragma unroll
        for (int k2 = 0; k2 < 8; ++k2)
            __builtin_amdgcn_global_load_lds((gas_t*)(src + k2 * 512),
                                             (las_t*)(dst + k2 * 512), 16, 0, 0);
    };
    // K A-frags for the 64 keys starting at j0
    auto load_ka = [&](int j0, short8* ka) {
#pragma unroll
        for (int kt = 0; kt < 2; ++kt)
#pragma unroll
            for (int dh = 0; dh < 2; ++dh)
                ka[kt * 2 + dh] = *(const short8*)(Q + (size_t)(j0 + kt * 32 + ln) * DQ
                                                   + dh * 16 + h * 8);
    };

    // persistent Q B-frags: bq[qh2][dh] = Q^T fragment for rows m0+qh2*32..+31
    short8 bq[2][2];
#pragma unroll
    for (int q2 = 0; q2 < 2; ++q2)
#pragma unroll
        for (int dh = 0; dh < 2; ++dh)
            bq[q2][dh] = *(const short8*)(Q + (size_t)(m0 + q2 * 32 + ln) * DQ
                                           + dh * 16 + h * 8);

    f32x16 zf;
#pragma unroll
    for (int r = 0; r < 16; ++r) zf[r] = 0.f;
    f32x16 o[2][8];
#pragma unroll
    for (int mt = 0; mt < 2; ++mt)
#pragma unroll
        for (int ct = 0; ct < 8; ++ct) o[mt][ct] = zf;
    float l_acc[2] = {0.f, 0.f};

    // S^T for 64 keys: C[kt][q2] = K-tile(kt) . Q^T(q2)
    f32x16 C[2][2];
    auto s_phase = [&](short8* ka) {
#pragma unroll
        for (int kt = 0; kt < 2; ++kt)
#pragma unroll
            for (int q2 = 0; q2 < 2; ++q2) {
                f32x16 c = __builtin_amdgcn_mfma_f32_32x32x16_bf16(
                               ka[kt * 2 + 0], bq[q2][0], zf, 0, 0, 0);
                C[kt][q2] = __builtin_amdgcn_mfma_f32_32x32x16_bf16(
                               ka[kt * 2 + 1], bq[q2][1], c, 0, 0, 0);
            }
    };
    // exp + pack: C regs [8a..8a+7] ARE the PV A-frag for key-group g=2kt+a
    short8 fr[4][2];
    auto exp_pack = [&]() {
#pragma unroll
        for (int kt = 0; kt < 2; ++kt)
#pragma unroll
            for (int q2 = 0; q2 < 2; ++q2) {
#pragma unroll
                for (int a = 0; a < 2; ++a) {
                    union { short8 s; u32 u[4]; } f;
#pragma unroll
                    for (int j = 0; j < 4; ++j) {
                        float e0 = exp2_fast(C[kt][q2][8 * a + 2 * j]);
                        float e1 = exp2_fast(C[kt][q2][8 * a + 2 * j + 1]);
                        l_acc[q2] += e0 + e1;
                        u32 u0 = __builtin_bit_cast(u32, e0) + 0x8000u;
                        u32 u1 = __builtin_bit_cast(u32, e1) + 0x8000u;
                        f.u[j] = __builtin_amdgcn_perm(u1, u0, 0x07060302);
                    }
                    fr[kt * 2 + a][q2] = f.s;
                }
            }
    };

    // ---- prologue ----
    short8 ka_cur[4], ka_next[4];
    load_ka(t64_0 * 64, ka_cur);
    stage(t64_0, 0);
    s_phase(ka_cur);
    exp_pack();                         // frags for tile 0
    load_ka(t64_0 * 64 + BK, ka_next);  // K for tile 1
    __syncthreads();                    // DMA(tile 0) complete

    for (int it = 0; it < NIT; ++it) {
        const int more = (it + 1 < NIT);
        if (more) {
            stage(t64_0 + it + 1, (it + 1) & 1);   // DMA for next tile, other buf
            s_phase(ka_next);                       // S^T(it+1) queued behind PV
            if (it + 2 < NIT) load_ka((t64_0 + it + 2) * 64, ka_next);
        }
        // ---- PV(it): 32 bv LDS reads, 64 MFMAs (each bv feeds both m-tiles) ----
        const unsigned short* vb = &Vbuf[it & 1][0] + (size_t)lane * 8;
#pragma unroll
        for (int g = 0; g < 4; ++g) {
#pragma unroll
            for (int ct = 0; ct < 8; ++ct) {
                short8 bv = *(const short8*)(vb + (g * 8 + ct) * 512);
                o[0][ct] = __builtin_amdgcn_mfma_f32_32x32x16_bf16(fr[g][0], bv, o[0][ct], 0, 0, 0);
                o[1][ct] = __builtin_amdgcn_mfma_f32_32x32x16_bf16(fr[g][1], bv, o[1][ct], 0, 0, 0);
            }
        }
        if (more) {
            exp_pack();        // VALU overlaps PV MFMAs in the pipe
            __syncthreads();   // next tile staged; all waves done with old buf
        }
    }

    // ---- l denom: q lives on lane axis -> one cross-half reduce ----
#pragma unroll
    for (int q2 = 0; q2 < 2; ++q2)
        l_acc[q2] += __shfl_xor(l_acc[q2], 32);
    if (h == 0) {
        atomicAdd(&lsum[(size_t)side * NR + m0 + ln], l_acc[0]);
        atomicAdd(&lsum[(size_t)side * NR + m0 + 32 + ln], l_acc[1]);
    }

    // ---- epilogue: 4 col-passes; O->bf16->Ebuf (A-layout), proj MFMA ----
    f32x16 pp[2][2];
    pp[0][0] = zf; pp[0][1] = zf; pp[1][0] = zf; pp[1][1] = zf;
    const unsigned short* wb_base = wbf + (size_t)side * 16384;
    unsigned short* Ew = Ebuf[w];
#pragma unroll
    for (int p = 0; p < 4; ++p) {
        __builtin_amdgcn_s_waitcnt(0xC07F);   // prior pass reads landed
#pragma unroll
        for (int mt = 0; mt < 2; ++mt)
#pragma unroll
            for (int c2 = 0; c2 < 2; ++c2)
#pragma unroll
                for (int r = 0; r < 16; ++r) {
                    int row = mt * 32 + (r & 3) + ((r >> 2) << 3) + h * 4;
                    Ew[row * 72 + c2 * 32 + ln] = f32_to_bf16(o[mt][2 * p + c2][r]);
                }
#pragma unroll
        for (int kt = 0; kt < 4; ++kt) {
            short8 a0 = *(const short8*)&Ew[ln * 72 + kt * 16 + h * 8];
            short8 a1 = *(const short8*)&Ew[(32 + ln) * 72 + kt * 16 + h * 8];
#pragma unroll
            for (int nt = 0; nt < 2; ++nt) {
                short8 bw = *(const short8*)(wb_base
                            + ((size_t)(p * 4 + kt) * 2 + nt) * 512 + (size_t)lane * 8);
                pp[0][nt] = __builtin_amdgcn_mfma_f32_32x32x16_bf16(a0, bw, pp[0][nt], 0, 0, 0);
                pp[1][nt] = __builtin_amdgcn_mfma_f32_32x32x16_bf16(a1, bw, pp[1][nt], 0, 0, 0);
            }
        }
    }

    // ---- atomic accumulate projected partials ----
#pragma unroll
    for (int mt = 0; mt < 2; ++mt)
#pragma unroll
        for (int nt = 0; nt < 2; ++nt)
#pragma unroll
            for (int r = 0; r < 16; ++r) {
                int row = (r & 3) + ((r >> 2) << 3) + h * 4;
                int gm  = m0 + mt * 32 + row;
                atomicAdd(&acc[((size_t)side * NR + gm) * OUT_DIM + nt * 32 + ln],
                          pp[mt][nt][r]);
            }
}

// ---------------------------------------------------------------------------
__global__ void final_kernel(const float4* __restrict__ acc,
                             const float* __restrict__ lsum,
                             float4* __restrict__ out) {
    int i4  = blockIdx.x * blockDim.x + threadIdx.x;   // 0..262143
    int row = i4 >> 4;
    float inv = 1.0f / lsum[row];
    float4 v = acc[i4];
    out[i4] = make_float4(fmaxf(v.x * inv, 0.f), fmaxf(v.y * inv, 0.f),
                          fmaxf(v.z * inv, 0.f), fmaxf(v.w * inv, 0.f));
}

// ---------------------------------------------------------------------------
extern "C" void kernel_launch(void* const* d_in, const int* in_sizes, int n_in,
                              void* d_out, int out_size, void* d_ws, size_t ws_size,
                              hipStream_t stream) {
    const float* review = (const float*)d_in[0];
    const float* user   = (const float*)d_in[1];
    const float* item   = (const float*)d_in[2];
    const int* adj_ur   = (const int*)d_in[3];
    const int* adj_ri   = (const int*)d_in[4];
    const int* adj_ir   = (const int*)d_in[5];
    const int* adj_ru   = (const int*)d_in[6];
    const float* Wu     = (const float*)d_in[7];
    const float* Wi     = (const float*)d_in[8];
    float* out = (float*)d_out;

    // ws: acc | lsum | vt | qh | wbf  (~13.2 MB)
    float* acc  = (float*)d_ws;
    float* lsum = acc + (size_t)2 * NR * OUT_DIM;
    unsigned short* vt  = (unsigned short*)(lsum + 2 * NR);
    unsigned short* qh  = vt + (size_t)2 * NR * DV;
    unsigned short* wbf = qh + (size_t)2 * NR * DQ;

    prep_gather_kernel<<<1824, 256, 0, stream>>>(
        review, user, item, adj_ur, adj_ri, adj_ir, adj_ru, Wu, Wi,
        (float4*)acc, qh, wbf, vt);
    flash_kernel<<<256, 256, 0, stream>>>(qh, vt, wbf, acc, lsum);
    final_kernel<<<1024, 256, 0, stream>>>((const float4*)acc, lsum, (float4*)out);
}

// Round 8
// 155.135 us; speedup vs baseline: 1.3067x; 1.3067x over previous
//
#include <hip/hip_runtime.h>
#include <math.h>

// ---------------------------------------------------------------------------
// AttentionAggregator round 8:
//  R7 post-mortem: S^T register-P worked, but 1 wave/SIMD killed MFMA/VALU
//  overlap (VALU 42us serialized behind MFMA 33us). R8 = R6 occupancy
//  (32-row waves, 8-wave blocks, 2 waves/SIMD) + R7 register-P:
//   - wave = 32 q-rows x 256 cols; S^T = K*Q^T puts q on the C lane axis;
//     C regs [8a..8a+7] are PV A-frags verbatim under the key permutation
//     baked into the V gather (proven in R7).
//   - LDS/CU-iter: bv 256KB + DMA 32KB (no P round-trip, no lgkm chain).
//   - NO atomics / NO zero-init: per-split partials opart/lpart with unique
//     writers; final sums 4 splits, divides, relu. Overhead was 63us in R7.
//  Spill sentinel: hbm_bytes (R4: spill = GBs of FETCH+WRITE).
// ---------------------------------------------------------------------------
#define NR 8192
#define DQ 32
#define DV 256
#define OUT_DIM 64
#define NSPLIT 4
#define BK 64
#define NIT ((NR / NSPLIT) / BK)      // 32
// 2^-1.25 * sqrt(log2(e)): qh = q*QS2 -> dot = (q.q')/sqrt(32)*log2(e); p=2^s
#define QSCALE2 0.5050114839784955f

typedef short short4v __attribute__((ext_vector_type(4)));
typedef short short8 __attribute__((ext_vector_type(8)));   // 8 bf16
typedef float f32x16 __attribute__((ext_vector_type(16)));  // 32x32 MFMA acc
typedef unsigned int u32;
typedef __attribute__((address_space(1))) const u32 gas_t;
typedef __attribute__((address_space(3))) u32 las_t;

__device__ __forceinline__ unsigned short f32_to_bf16(float f) {
    union { float f; unsigned int u; } v; v.f = f;
    unsigned int u = v.u + 0x7FFFu + ((v.u >> 16) & 1u);    // RNE
    return (unsigned short)(u >> 16);
}
__device__ __forceinline__ float exp2_fast(float x) {
#if __has_builtin(__builtin_amdgcn_exp2f)
    return __builtin_amdgcn_exp2f(x);
#else
    return exp2f(x);
#endif
}

// ---------------------------------------------------------------------------
// prep: [0,256) gather (FIRST: longest blocks start at t=0) |
//       [256,768) qconv | [768,784) wconv.  No zeroing needed anywhere.
// ---------------------------------------------------------------------------
__global__ void prep_kernel(
        const float* __restrict__ review,
        const float* __restrict__ user,
        const float* __restrict__ item,
        const int* __restrict__ adj_ur, const int* __restrict__ adj_ri,
        const int* __restrict__ adj_ir, const int* __restrict__ adj_ru,
        const float* __restrict__ Wu,  const float* __restrict__ Wi,
        unsigned short* __restrict__ qh,
        unsigned short* __restrict__ wbf,
        unsigned short* __restrict__ vt) {
    __shared__ __align__(16) unsigned short T[64][264];
    int b = blockIdx.x, t = threadIdx.x;
    if (b < 256) {
        // ---- gather: one side x 64 keys -> one 32 KB permuted vt tile ----
        int side = b >> 7;
        int bxg  = b & 127;
        int key0 = bxg * 64;
        const int* adjA   = side ? adj_ir : adj_ur;
        const int* adjB   = side ? adj_ru : adj_ri;
        const float* srcB = side ? user : item;
        // phase 1: coalesced row reads -> bf16 LDS tile T[key][c]
        {
            int key = t >> 2, q = t & 3;
#pragma unroll
            for (int rr = 0; rr < 2; ++rr) {
                int ss  = q * 2 + rr;
                int knb = ss >> 1, isB = ss & 1;
                int row = (isB ? adjB : adjA)[(key0 + key) * 4 + knb];
                const float4* src = (const float4*)((isB ? srcB : review) + (size_t)row * DQ);
                int dbase = knb * 64 + isB * 32;
#pragma unroll
                for (int d = 0; d < 4; ++d) {
                    float4 a = src[d * 2], b2 = src[d * 2 + 1];
                    short8 v;
                    v[0] = (short)f32_to_bf16(a.x);  v[1] = (short)f32_to_bf16(a.y);
                    v[2] = (short)f32_to_bf16(a.z);  v[3] = (short)f32_to_bf16(a.w);
                    v[4] = (short)f32_to_bf16(b2.x); v[5] = (short)f32_to_bf16(b2.y);
                    v[6] = (short)f32_to_bf16(b2.z); v[7] = (short)f32_to_bf16(b2.w);
                    *(short8*)&T[key][dbase + d * 8] = v;
                }
            }
        }
        __syncthreads();
        // phase 2: permuted frag-native writes (R7-verified permutation):
        // B-frag (g,ct,lane=(ln,h),i) = V[32kt+16a+4h+8(i>>2)+(i&3)][ct*32+ln]
#pragma unroll
        for (int w8 = 0; w8 < 8; ++w8) {
            int u    = t + 256 * w8;          // 0..2047
            int g    = u >> 9;
            int ct   = (u >> 6) & 7;
            int lane = u & 63;
            int ln = lane & 31, h = lane >> 5;
            int kt = g >> 1, a = g & 1;
            int col = ct * 32 + ln;
            short8 v;
#pragma unroll
            for (int i = 0; i < 8; ++i) {
                int lkey = kt * 32 + a * 16 + h * 4 + 8 * (i >> 2) + (i & 3);
                v[i] = (short)T[lkey][col];
            }
            size_t dst = (size_t)side * NR * DV + (size_t)bxg * 16384 + (size_t)u * 8;
            *(short8*)(vt + dst) = v;
        }
        return;
    }
    b -= 256;
    if (b < 512) {                        // qconv
        int i = (b * 256 + t) * 4;
        int side  = i >= NR * DQ;
        int local = i - side * NR * DQ;
        const float* src = side ? item : user;
        float4 v = *(const float4*)(src + local);
        short4v o;
        o[0] = (short)f32_to_bf16(v.x * QSCALE2);
        o[1] = (short)f32_to_bf16(v.y * QSCALE2);
        o[2] = (short)f32_to_bf16(v.z * QSCALE2);
        o[3] = (short)f32_to_bf16(v.w * QSCALE2);
        *(short4v*)(qh + i) = o;
        return;
    }
    b -= 512;                             // wconv: wbf[wm][p][kt][nt][lane][i]
    int g  = b * 256 + t;
    int ln = g & 31, h = (g >> 5) & 1, nt = (g >> 6) & 1;
    int kt = (g >> 7) & 3, p = (g >> 9) & 3, wm = g >> 11;
    const float* W = wm ? Wi : Wu;
    unsigned short* dst = wbf + (size_t)g * 8;
#pragma unroll
    for (int i = 0; i < 8; ++i) {
        int k = p * 64 + kt * 16 + h * 8 + i;
        dst[i] = f32_to_bf16(W[k * OUT_DIM + nt * 32 + ln]);
    }
}

// ---------------------------------------------------------------------------
// Flash attention: 8-wave blocks (512 thr), 256 blocks (1/CU, 2 waves/SIMD).
// bx&7 = side + 2*sp (XCD-affine), rb = bx>>3. Wave = 32 rows x 256 cols.
// Per 64-key iter: stage(it+1) DMA -> S^T(it+1) [4 MFMA] -> PV(it)
// [32 bv ds_read_b128, 32 MFMA] -> exp_pack(it+1) [VALU, overlapped by the
// sibling wave's MFMAs] -> barrier.
// ---------------------------------------------------------------------------
__global__ __launch_bounds__(512, 2) void flash_kernel(
        const unsigned short* __restrict__ qh,
        const unsigned short* __restrict__ vt,
        const unsigned short* __restrict__ wbf,
        float* __restrict__ opart,   // [NSPLIT][2][NR][64]
        float* __restrict__ lpart)   // [NSPLIT][2][NR]
{
    const int bx   = blockIdx.x;
    const int side = bx & 1;
    const int sp   = (bx >> 1) & (NSPLIT - 1);
    const int rb   = bx >> 3;                  // 0..31
    const int w    = threadIdx.x >> 6;         // 0..7
    const int lane = threadIdx.x & 63;
    const int ln   = lane & 31;
    const int h    = lane >> 5;

    const int m0 = rb * 256 + w * 32;          // wave's first q-row
    const unsigned short* Q  = qh + (size_t)side * NR * DQ;
    const unsigned short* VT = vt + (size_t)side * NR * DV;
    const int t64_0 = sp * NIT;                // first 64-key tile index

    __shared__ __align__(16) unsigned short Vbuf[2][16384];   // 64 KB
    __shared__ __align__(16) unsigned short Ebuf[8][32 * 72]; // 36.9 KB

    // stage 64-key tile into Vbuf[b]: each wave DMAs its 4 KB slice
    auto stage = [&](int tile, int b) {
        const unsigned short* src = VT + (size_t)tile * 16384 + w * 2048 + lane * 8;
        unsigned short* dst = &Vbuf[b][w * 2048];
#pragma unroll
        for (int k2 = 0; k2 < 4; ++k2)
            __builtin_amdgcn_global_load_lds((gas_t*)(src + k2 * 512),
                                             (las_t*)(dst + k2 * 512), 16, 0, 0);
    };
    // K A-frags for 64 keys at j0
    auto load_ka = [&](int j0, short8* ka) {
#pragma unroll
        for (int kt = 0; kt < 2; ++kt)
#pragma unroll
            for (int dh = 0; dh < 2; ++dh)
                ka[kt * 2 + dh] = *(const short8*)(Q + (size_t)(j0 + kt * 32 + ln) * DQ
                                                   + dh * 16 + h * 8);
    };

    // persistent Q B-frags for this wave's 32 rows
    short8 bq[2];
#pragma unroll
    for (int dh = 0; dh < 2; ++dh)
        bq[dh] = *(const short8*)(Q + (size_t)(m0 + ln) * DQ + dh * 16 + h * 8);

    f32x16 zf;
#pragma unroll
    for (int r = 0; r < 16; ++r) zf[r] = 0.f;
    f32x16 o[8];
#pragma unroll
    for (int ct = 0; ct < 8; ++ct) o[ct] = zf;
    float l_acc = 0.f;

    // S^T: C[kt] = K-tile(kt) . Q^T  (q on lane axis, key on reg axis)
    f32x16 C[2];
    auto s_phase = [&](short8* ka) {
#pragma unroll
        for (int kt = 0; kt < 2; ++kt) {
            f32x16 c = __builtin_amdgcn_mfma_f32_32x32x16_bf16(
                           ka[kt * 2 + 0], bq[0], zf, 0, 0, 0);
            C[kt] = __builtin_amdgcn_mfma_f32_32x32x16_bf16(
                           ka[kt * 2 + 1], bq[1], c, 0, 0, 0);
        }
    };
    // exp + pack: C regs [8a..8a+7] ARE the PV A-frag for key-group g=2kt+a
    short8 fr[4];
    auto exp_pack = [&]() {
#pragma unroll
        for (int kt = 0; kt < 2; ++kt)
#pragma unroll
            for (int a = 0; a < 2; ++a) {
                union { short8 s; u32 u[4]; } f;
#pragma unroll
                for (int j = 0; j < 4; ++j) {
                    float e0 = exp2_fast(C[kt][8 * a + 2 * j]);
                    float e1 = exp2_fast(C[kt][8 * a + 2 * j + 1]);
                    l_acc += e0 + e1;
                    u32 u0 = __builtin_bit_cast(u32, e0) + 0x8000u;
                    u32 u1 = __builtin_bit_cast(u32, e1) + 0x8000u;
                    f.u[j] = __builtin_amdgcn_perm(u1, u0, 0x07060302);
                }
                fr[kt * 2 + a] = f.s;
            }
    };

    // ---- prologue ----
    short8 ka_buf[4];
    load_ka(t64_0 * 64, ka_buf);
    stage(t64_0, 0);
    s_phase(ka_buf);
    exp_pack();                          // fr for tile 0
    load_ka(t64_0 * 64 + BK, ka_buf);    // K for tile 1
    __syncthreads();                     // DMA(tile 0) landed

    for (int it = 0; it < NIT; ++it) {
        const int more = (it + 1 < NIT);
        if (more) {
            stage(t64_0 + it + 1, (it + 1) & 1);
            s_phase(ka_buf);                               // C(it+1)
            if (it + 2 < NIT) load_ka((t64_0 + it + 2) * 64, ka_buf);
        }
        // ---- PV(it): 32 bv reads, 32 MFMAs ----
        const unsigned short* vb = &Vbuf[it & 1][0] + (size_t)lane * 8;
#pragma unroll
        for (int g = 0; g < 4; ++g) {
#pragma unroll
            for (int ct = 0; ct < 8; ++ct) {
                short8 bv = *(const short8*)(vb + (g * 8 + ct) * 512);
                o[ct] = __builtin_amdgcn_mfma_f32_32x32x16_bf16(fr[g], bv, o[ct], 0, 0, 0);
            }
        }
        if (more) {
            exp_pack();        // fr <- C(it+1); sibling wave's MFMAs overlap
            __syncthreads();   // next tile staged; all waves done with old buf
        }
    }

    // ---- l: q on lane axis -> one cross-half reduce; unique writer ----
    l_acc += __shfl_xor(l_acc, 32);
    if (h == 0)
        lpart[(size_t)(sp * 2 + side) * NR + m0 + ln] = l_acc;

    // ---- epilogue: 4 col-passes; O->bf16->Ebuf (A-layout), proj MFMA ----
    f32x16 pp[2];
    pp[0] = zf; pp[1] = zf;
    const unsigned short* wb_base = wbf + (size_t)side * 16384;
    unsigned short* Ew = Ebuf[w];
#pragma unroll
    for (int p = 0; p < 4; ++p) {
        __builtin_amdgcn_s_waitcnt(0xC07F);   // prior pass's Ew reads landed
#pragma unroll
        for (int c2 = 0; c2 < 2; ++c2)
#pragma unroll
            for (int r = 0; r < 16; ++r) {
                int row = (r & 3) + ((r >> 2) << 3) + h * 4;
                Ew[row * 72 + c2 * 32 + ln] = f32_to_bf16(o[2 * p + c2][r]);
            }
#pragma unroll
        for (int kt = 0; kt < 4; ++kt) {
            short8 a = *(const short8*)&Ew[ln * 72 + kt * 16 + h * 8];
#pragma unroll
            for (int nt = 0; nt < 2; ++nt) {
                short8 bw = *(const short8*)(wb_base
                            + ((size_t)(p * 4 + kt) * 2 + nt) * 512 + (size_t)lane * 8);
                pp[nt] = __builtin_amdgcn_mfma_f32_32x32x16_bf16(a, bw, pp[nt], 0, 0, 0);
            }
        }
    }

    // ---- store projected partials (unique writer, no atomics) ----
    float* op = opart + ((size_t)(sp * 2 + side) * NR + m0) * OUT_DIM;
#pragma unroll
    for (int nt = 0; nt < 2; ++nt)
#pragma unroll
        for (int r = 0; r < 16; ++r) {
            int row = (r & 3) + ((r >> 2) << 3) + h * 4;
            op[(size_t)row * OUT_DIM + nt * 32 + ln] = pp[nt][r];
        }
}

// ---------------------------------------------------------------------------
// final: out = relu( (sum_sp opart) / (sum_sp lpart) ), float4 per thread.
// ---------------------------------------------------------------------------
__global__ void final_kernel(const float4* __restrict__ opart,
                             const float* __restrict__ lpart,
                             float4* __restrict__ out) {
    int i4  = blockIdx.x * blockDim.x + threadIdx.x;   // 0..262143
    int row = i4 >> 4;                                  // side*NR + m, 0..16383
    float4 v = make_float4(0.f, 0.f, 0.f, 0.f);
    float L = 0.f;
#pragma unroll
    for (int sp = 0; sp < NSPLIT; ++sp) {
        float4 a = opart[(size_t)sp * (2 * NR * 16) + i4];
        v.x += a.x; v.y += a.y; v.z += a.z; v.w += a.w;
        L += lpart[(size_t)sp * (2 * NR) + row];
    }
    float inv = 1.0f / L;
    out[i4] = make_float4(fmaxf(v.x * inv, 0.f), fmaxf(v.y * inv, 0.f),
                          fmaxf(v.z * inv, 0.f), fmaxf(v.w * inv, 0.f));
}

// ---------------------------------------------------------------------------
extern "C" void kernel_launch(void* const* d_in, const int* in_sizes, int n_in,
                              void* d_out, int out_size, void* d_ws, size_t ws_size,
                              hipStream_t stream) {
    const float* review = (const float*)d_in[0];
    const float* user   = (const float*)d_in[1];
    const float* item   = (const float*)d_in[2];
    const int* adj_ur   = (const int*)d_in[3];
    const int* adj_ri   = (const int*)d_in[4];
    const int* adj_ir   = (const int*)d_in[5];
    const int* adj_ru   = (const int*)d_in[6];
    const float* Wu     = (const float*)d_in[7];
    const float* Wi     = (const float*)d_in[8];
    float* out = (float*)d_out;

    // ws: opart 16MB | lpart 256KB | vt 8MB | qh 1MB | wbf 64KB  (~25.3 MB)
    float* opart = (float*)d_ws;
    float* lpart = opart + (size_t)NSPLIT * 2 * NR * OUT_DIM;
    unsigned short* vt  = (unsigned short*)(lpart + (size_t)NSPLIT * 2 * NR);
    unsigned short* qh  = vt + (size_t)2 * NR * DV;
    unsigned short* wbf = qh + (size_t)2 * NR * DQ;

    prep_kernel<<<784, 256, 0, stream>>>(
        review, user, item, adj_ur, adj_ri, adj_ir, adj_ru, Wu, Wi,
        qh, wbf, vt);
    flash_kernel<<<256, 512, 0, stream>>>(qh, vt, wbf, opart, lpart);
    final_kernel<<<1024, 256, 0, stream>>>((const float4*)opart, lpart, (float4*)out);
}

// Round 9
// 153.944 us; speedup vs baseline: 1.3168x; 1.0077x over previous
//
#include <hip/hip_runtime.h>
#include <math.h>

// ---------------------------------------------------------------------------
// AttentionAggregator round 9:
//  R8 post-mortem: loop body serialized phases (PV MFMAs, THEN exp VALU) and
//  both waves/SIMD sit at the same barrier -> same phase simultaneously ->
//  matrix idles during exp, VALU idles during PV (iter 6540 cyc vs 3400 model).
//  R9 = R8 with the exp/pack for iteration it+1 interleaved INTO the PV MFMA
//  stream of iteration it, one group at a time, overwriting fr[g] in place
//  right after PV group g's MFMAs issue (fr[g]'s last use) -> zero extra
//  registers (R8 is at ~252/256 unified regs; a double buffer would spill).
//  Everything else identical to R8 (one variable per round).
// ---------------------------------------------------------------------------
#define NR 8192
#define DQ 32
#define DV 256
#define OUT_DIM 64
#define NSPLIT 4
#define BK 64
#define NIT ((NR / NSPLIT) / BK)      // 32
// 2^-1.25 * sqrt(log2(e)): qh = q*QS2 -> dot = (q.q')/sqrt(32)*log2(e); p=2^s
#define QSCALE2 0.5050114839784955f

typedef short short4v __attribute__((ext_vector_type(4)));
typedef short short8 __attribute__((ext_vector_type(8)));   // 8 bf16
typedef float f32x16 __attribute__((ext_vector_type(16)));  // 32x32 MFMA acc
typedef unsigned int u32;
typedef __attribute__((address_space(1))) const u32 gas_t;
typedef __attribute__((address_space(3))) u32 las_t;

__device__ __forceinline__ unsigned short f32_to_bf16(float f) {
    union { float f; unsigned int u; } v; v.f = f;
    unsigned int u = v.u + 0x7FFFu + ((v.u >> 16) & 1u);    // RNE
    return (unsigned short)(u >> 16);
}
__device__ __forceinline__ float exp2_fast(float x) {
#if __has_builtin(__builtin_amdgcn_exp2f)
    return __builtin_amdgcn_exp2f(x);
#else
    return exp2f(x);
#endif
}

// ---------------------------------------------------------------------------
// prep: [0,256) gather | [256,768) qconv | [768,784) wconv. No zeroing.
// ---------------------------------------------------------------------------
__global__ void prep_kernel(
        const float* __restrict__ review,
        const float* __restrict__ user,
        const float* __restrict__ item,
        const int* __restrict__ adj_ur, const int* __restrict__ adj_ri,
        const int* __restrict__ adj_ir, const int* __restrict__ adj_ru,
        const float* __restrict__ Wu,  const float* __restrict__ Wi,
        unsigned short* __restrict__ qh,
        unsigned short* __restrict__ wbf,
        unsigned short* __restrict__ vt) {
    __shared__ __align__(16) unsigned short T[64][264];
    int b = blockIdx.x, t = threadIdx.x;
    if (b < 256) {
        // ---- gather: one side x 64 keys -> one 32 KB permuted vt tile ----
        int side = b >> 7;
        int bxg  = b & 127;
        int key0 = bxg * 64;
        const int* adjA   = side ? adj_ir : adj_ur;
        const int* adjB   = side ? adj_ru : adj_ri;
        const float* srcB = side ? user : item;
        {
            int key = t >> 2, q = t & 3;
#pragma unroll
            for (int rr = 0; rr < 2; ++rr) {
                int ss  = q * 2 + rr;
                int knb = ss >> 1, isB = ss & 1;
                int row = (isB ? adjB : adjA)[(key0 + key) * 4 + knb];
                const float4* src = (const float4*)((isB ? srcB : review) + (size_t)row * DQ);
                int dbase = knb * 64 + isB * 32;
#pragma unroll
                for (int d = 0; d < 4; ++d) {
                    float4 a = src[d * 2], b2 = src[d * 2 + 1];
                    short8 v;
                    v[0] = (short)f32_to_bf16(a.x);  v[1] = (short)f32_to_bf16(a.y);
                    v[2] = (short)f32_to_bf16(a.z);  v[3] = (short)f32_to_bf16(a.w);
                    v[4] = (short)f32_to_bf16(b2.x); v[5] = (short)f32_to_bf16(b2.y);
                    v[6] = (short)f32_to_bf16(b2.z); v[7] = (short)f32_to_bf16(b2.w);
                    *(short8*)&T[key][dbase + d * 8] = v;
                }
            }
        }
        __syncthreads();
        // phase 2: permuted frag-native writes (R7/R8-verified permutation):
        // B-frag (g,ct,lane=(ln,h),i) = V[32kt+16a+4h+8(i>>2)+(i&3)][ct*32+ln]
#pragma unroll
        for (int w8 = 0; w8 < 8; ++w8) {
            int u    = t + 256 * w8;          // 0..2047
            int g    = u >> 9;
            int ct   = (u >> 6) & 7;
            int lane = u & 63;
            int ln = lane & 31, h = lane >> 5;
            int kt = g >> 1, a = g & 1;
            int col = ct * 32 + ln;
            short8 v;
#pragma unroll
            for (int i = 0; i < 8; ++i) {
                int lkey = kt * 32 + a * 16 + h * 4 + 8 * (i >> 2) + (i & 3);
                v[i] = (short)T[lkey][col];
            }
            size_t dst = (size_t)side * NR * DV + (size_t)bxg * 16384 + (size_t)u * 8;
            *(short8*)(vt + dst) = v;
        }
        return;
    }
    b -= 256;
    if (b < 512) {                        // qconv
        int i = (b * 256 + t) * 4;
        int side  = i >= NR * DQ;
        int local = i - side * NR * DQ;
        const float* src = side ? item : user;
        float4 v = *(const float4*)(src + local);
        short4v o;
        o[0] = (short)f32_to_bf16(v.x * QSCALE2);
        o[1] = (short)f32_to_bf16(v.y * QSCALE2);
        o[2] = (short)f32_to_bf16(v.z * QSCALE2);
        o[3] = (short)f32_to_bf16(v.w * QSCALE2);
        *(short4v*)(qh + i) = o;
        return;
    }
    b -= 512;                             // wconv: wbf[wm][p][kt][nt][lane][i]
    int g  = b * 256 + t;
    int ln = g & 31, h = (g >> 5) & 1, nt = (g >> 6) & 1;
    int kt = (g >> 7) & 3, p = (g >> 9) & 3, wm = g >> 11;
    const float* W = wm ? Wi : Wu;
    unsigned short* dst = wbf + (size_t)g * 8;
#pragma unroll
    for (int i = 0; i < 8; ++i) {
        int k = p * 64 + kt * 16 + h * 8 + i;
        dst[i] = f32_to_bf16(W[k * OUT_DIM + nt * 32 + ln]);
    }
}

// ---------------------------------------------------------------------------
// Flash attention: 8-wave blocks (512 thr), 256 blocks (1/CU, 2 waves/SIMD).
// bx&7 = side + 2*sp (XCD-affine), rb = bx>>3. Wave = 32 rows x 256 cols.
// Per 64-key iter body (interleaved):
//   stage(it+1) DMA | S^T(it+1) 4 MFMA -> C |
//   for g=0..3: [8 bv ds_read + 8 PV MFMA with fr[g]] [exp chunk g: C -> fr[g]]
//   barrier.
// exp chunk g overwrites fr[g] right after its last use -> no double buffer,
// and the VALU exp executes while the matrix queue drains the PV MFMAs.
// ---------------------------------------------------------------------------
__global__ __launch_bounds__(512, 2) void flash_kernel(
        const unsigned short* __restrict__ qh,
        const unsigned short* __restrict__ vt,
        const unsigned short* __restrict__ wbf,
        float* __restrict__ opart,   // [NSPLIT][2][NR][64]
        float* __restrict__ lpart)   // [NSPLIT][2][NR]
{
    const int bx   = blockIdx.x;
    const int side = bx & 1;
    const int sp   = (bx >> 1) & (NSPLIT - 1);
    const int rb   = bx >> 3;                  // 0..31
    const int w    = threadIdx.x >> 6;         // 0..7
    const int lane = threadIdx.x & 63;
    const int ln   = lane & 31;
    const int h    = lane >> 5;

    const int m0 = rb * 256 + w * 32;          // wave's first q-row
    const unsigned short* Q  = qh + (size_t)side * NR * DQ;
    const unsigned short* VT = vt + (size_t)side * NR * DV;
    const int t64_0 = sp * NIT;                // first 64-key tile index

    __shared__ __align__(16) unsigned short Vbuf[2][16384];   // 64 KB
    __shared__ __align__(16) unsigned short Ebuf[8][32 * 72]; // 36.9 KB

    auto stage = [&](int tile, int b) {
        const unsigned short* src = VT + (size_t)tile * 16384 + w * 2048 + lane * 8;
        unsigned short* dst = &Vbuf[b][w * 2048];
#pragma unroll
        for (int k2 = 0; k2 < 4; ++k2)
            __builtin_amdgcn_global_load_lds((gas_t*)(src + k2 * 512),
                                             (las_t*)(dst + k2 * 512), 16, 0, 0);
    };
    auto load_ka = [&](int j0, short8* ka) {
#pragma unroll
        for (int kt = 0; kt < 2; ++kt)
#pragma unroll
            for (int dh = 0; dh < 2; ++dh)
                ka[kt * 2 + dh] = *(const short8*)(Q + (size_t)(j0 + kt * 32 + ln) * DQ
                                                   + dh * 16 + h * 8);
    };

    // persistent Q B-frags for this wave's 32 rows
    short8 bq[2];
#pragma unroll
    for (int dh = 0; dh < 2; ++dh)
        bq[dh] = *(const short8*)(Q + (size_t)(m0 + ln) * DQ + dh * 16 + h * 8);

    f32x16 zf;
#pragma unroll
    for (int r = 0; r < 16; ++r) zf[r] = 0.f;
    f32x16 o[8];
#pragma unroll
    for (int ct = 0; ct < 8; ++ct) o[ct] = zf;
    float l_acc = 0.f;

    short8 fr[4];
    short8 ka_buf[4];

    // exp chunk g: C regs [8a..8a+7] (a=g&1, C half = g>>1) -> fr[g]
    auto exp_chunk = [&](const f32x16& Cs, int g) {
        int a = g & 1;
        union { short8 s; u32 u[4]; } f;
#pragma unroll
        for (int j = 0; j < 4; ++j) {
            float e0 = exp2_fast(Cs[8 * a + 2 * j]);
            float e1 = exp2_fast(Cs[8 * a + 2 * j + 1]);
            l_acc += e0 + e1;
            u32 u0 = __builtin_bit_cast(u32, e0) + 0x8000u;
            u32 u1 = __builtin_bit_cast(u32, e1) + 0x8000u;
            f.u[j] = __builtin_amdgcn_perm(u1, u0, 0x07060302);
        }
        fr[g] = f.s;
    };

    // ---- prologue: fr for tile 0 ----
    {
        load_ka(t64_0 * 64, ka_buf);
        stage(t64_0, 0);
        f32x16 c0 = __builtin_amdgcn_mfma_f32_32x32x16_bf16(ka_buf[0], bq[0], zf, 0, 0, 0);
        c0 = __builtin_amdgcn_mfma_f32_32x32x16_bf16(ka_buf[1], bq[1], c0, 0, 0, 0);
        f32x16 c1 = __builtin_amdgcn_mfma_f32_32x32x16_bf16(ka_buf[2], bq[0], zf, 0, 0, 0);
        c1 = __builtin_amdgcn_mfma_f32_32x32x16_bf16(ka_buf[3], bq[1], c1, 0, 0, 0);
        exp_chunk(c0, 0); exp_chunk(c0, 1);
        exp_chunk(c1, 2); exp_chunk(c1, 3);
        load_ka(t64_0 * 64 + BK, ka_buf);    // K for tile 1
    }
    __syncthreads();                         // DMA(tile 0) landed

    for (int it = 0; it < NIT; ++it) {
        const int more = (it + 1 < NIT);
        f32x16 C0, C1;
        if (more) {
            stage(t64_0 + it + 1, (it + 1) & 1);
            // S^T(it+1): issued ahead of PV so C is ready when exp chunks run
            C0 = __builtin_amdgcn_mfma_f32_32x32x16_bf16(ka_buf[0], bq[0], zf, 0, 0, 0);
            C0 = __builtin_amdgcn_mfma_f32_32x32x16_bf16(ka_buf[1], bq[1], C0, 0, 0, 0);
            C1 = __builtin_amdgcn_mfma_f32_32x32x16_bf16(ka_buf[2], bq[0], zf, 0, 0, 0);
            C1 = __builtin_amdgcn_mfma_f32_32x32x16_bf16(ka_buf[3], bq[1], C1, 0, 0, 0);
            if (it + 2 < NIT) load_ka((t64_0 + it + 2) * 64, ka_buf);
        }
        // ---- PV(it) with exp(it+1) interleaved per group ----
        const unsigned short* vb = &Vbuf[it & 1][0] + (size_t)lane * 8;
#pragma unroll
        for (int g = 0; g < 4; ++g) {
#pragma unroll
            for (int ct = 0; ct < 8; ++ct) {
                short8 bv = *(const short8*)(vb + (g * 8 + ct) * 512);
                o[ct] = __builtin_amdgcn_mfma_f32_32x32x16_bf16(fr[g], bv, o[ct], 0, 0, 0);
            }
            if (more) exp_chunk((g < 2) ? C0 : C1, g);   // fr[g] dead -> refill
        }
        if (more) __syncthreads();   // next tile staged; all waves off old buf
    }

    // ---- l: q on lane axis -> one cross-half reduce; unique writer ----
    l_acc += __shfl_xor(l_acc, 32);
    if (h == 0)
        lpart[(size_t)(sp * 2 + side) * NR + m0 + ln] = l_acc;

    // ---- epilogue: 4 col-passes; O->bf16->Ebuf (A-layout), proj MFMA ----
    f32x16 pp[2];
    pp[0] = zf; pp[1] = zf;
    const unsigned short* wb_base = wbf + (size_t)side * 16384;
    unsigned short* Ew = Ebuf[w];
#pragma unroll
    for (int p = 0; p < 4; ++p) {
        __builtin_amdgcn_s_waitcnt(0xC07F);   // prior pass's Ew reads landed
#pragma unroll
        for (int c2 = 0; c2 < 2; ++c2)
#pragma unroll
            for (int r = 0; r < 16; ++r) {
                int row = (r & 3) + ((r >> 2) << 3) + h * 4;
                Ew[row * 72 + c2 * 32 + ln] = f32_to_bf16(o[2 * p + c2][r]);
            }
#pragma unroll
        for (int kt = 0; kt < 4; ++kt) {
            short8 a = *(const short8*)&Ew[ln * 72 + kt * 16 + h * 8];
#pragma unroll
            for (int nt = 0; nt < 2; ++nt) {
                short8 bw = *(const short8*)(wb_base
                            + ((size_t)(p * 4 + kt) * 2 + nt) * 512 + (size_t)lane * 8);
                pp[nt] = __builtin_amdgcn_mfma_f32_32x32x16_bf16(a, bw, pp[nt], 0, 0, 0);
            }
        }
    }

    // ---- store projected partials (unique writer, no atomics) ----
    float* op = opart + ((size_t)(sp * 2 + side) * NR + m0) * OUT_DIM;
#pragma unroll
    for (int nt = 0; nt < 2; ++nt)
#pragma unroll
        for (int r = 0; r < 16; ++r) {
            int row = (r & 3) + ((r >> 2) << 3) + h * 4;
            op[(size_t)row * OUT_DIM + nt * 32 + ln] = pp[nt][r];
        }
}

// ---------------------------------------------------------------------------
// final: out = relu( (sum_sp opart) / (sum_sp lpart) ), float4 per thread.
// ---------------------------------------------------------------------------
__global__ void final_kernel(const float4* __restrict__ opart,
                             const float* __restrict__ lpart,
                             float4* __restrict__ out) {
    int i4  = blockIdx.x * blockDim.x + threadIdx.x;   // 0..262143
    int row = i4 >> 4;                                  // side*NR + m
    float4 v = make_float4(0.f, 0.f, 0.f, 0.f);
    float L = 0.f;
#pragma unroll
    for (int sp = 0; sp < NSPLIT; ++sp) {
        float4 a = opart[(size_t)sp * (2 * NR * 16) + i4];
        v.x += a.x; v.y += a.y; v.z += a.z; v.w += a.w;
        L += lpart[(size_t)sp * (2 * NR) + row];
    }
    float inv = 1.0f / L;
    out[i4] = make_float4(fmaxf(v.x * inv, 0.f), fmaxf(v.y * inv, 0.f),
                          fmaxf(v.z * inv, 0.f), fmaxf(v.w * inv, 0.f));
}

// ---------------------------------------------------------------------------
extern "C" void kernel_launch(void* const* d_in, const int* in_sizes, int n_in,
                              void* d_out, int out_size, void* d_ws, size_t ws_size,
                              hipStream_t stream) {
    const float* review = (const float*)d_in[0];
    const float* user   = (const float*)d_in[1];
    const float* item   = (const float*)d_in[2];
    const int* adj_ur   = (const int*)d_in[3];
    const int* adj_ri   = (const int*)d_in[4];
    const int* adj_ir   = (const int*)d_in[5];
    const int* adj_ru   = (const int*)d_in[6];
    const float* Wu     = (const float*)d_in[7];
    const float* Wi     = (const float*)d_in[8];
    float* out = (float*)d_out;

    // ws: opart 16MB | lpart 256KB | vt 8MB | qh 1MB | wbf 64KB  (~25.3 MB)
    float* opart = (float*)d_ws;
    float* lpart = opart + (size_t)NSPLIT * 2 * NR * OUT_DIM;
    unsigned short* vt  = (unsigned short*)(lpart + (size_t)NSPLIT * 2 * NR);
    unsigned short* qh  = vt + (size_t)2 * NR * DV;
    unsigned short* wbf = qh + (size_t)2 * NR * DQ;

    prep_kernel<<<784, 256, 0, stream>>>(
        review, user, item, adj_ur, adj_ri, adj_ir, adj_ru, Wu, Wi,
        qh, wbf, vt);
    flash_kernel<<<256, 512, 0, stream>>>(qh, vt, wbf, opart, lpart);
    final_kernel<<<1024, 256, 0, stream>>>((const float4*)opart, lpart, (float4*)out);
}